// Round 8
// baseline (153.958 us; speedup 1.0000x reference)
//
#include <hip/hip_runtime.h>
#include <stdint.h>
#include <float.h>
#include <math.h>

// Problem constants (b_n=2, f_num=4, N=50, C_in=256, C=64, h=200, w=336)
#define HW_TOT 67200   // h*w
#define NBF 8          // n = b_n*f_num
#define CO 64          // C
#define CI 256         // C_in
#define NN 50          // N
#define KK 200         // K = N*f_num
#define BN 2           // b_n
#define CHUNK 8        // c-rows per staged chunk

// ---------------------------------------------------------------------------
// Threefry-2x32, 20 rounds (JAX partitionable threefry semantics) — verified R1
// ---------------------------------------------------------------------------
__device__ __forceinline__ uint32_t rotl32(uint32_t v, int n) {
  return (v << n) | (v >> (32 - n));
}

__device__ void tf2x32(uint32_t k0, uint32_t k1, uint32_t x0, uint32_t x1,
                       uint32_t& o0, uint32_t& o1) {
  const uint32_t ks2 = k0 ^ k1 ^ 0x1BD11BDAu;
  x0 += k0; x1 += k1;
  x0 += x1; x1 = rotl32(x1, 13); x1 ^= x0;
  x0 += x1; x1 = rotl32(x1, 15); x1 ^= x0;
  x0 += x1; x1 = rotl32(x1, 26); x1 ^= x0;
  x0 += x1; x1 = rotl32(x1, 6);  x1 ^= x0;
  x0 += k1; x1 += ks2 + 1u;
  x0 += x1; x1 = rotl32(x1, 17); x1 ^= x0;
  x0 += x1; x1 = rotl32(x1, 29); x1 ^= x0;
  x0 += x1; x1 = rotl32(x1, 16); x1 ^= x0;
  x0 += x1; x1 = rotl32(x1, 24); x1 ^= x0;
  x0 += ks2; x1 += k0 + 2u;
  x0 += x1; x1 = rotl32(x1, 13); x1 ^= x0;
  x0 += x1; x1 = rotl32(x1, 15); x1 ^= x0;
  x0 += x1; x1 = rotl32(x1, 26); x1 ^= x0;
  x0 += x1; x1 = rotl32(x1, 6);  x1 ^= x0;
  x0 += k0; x1 += k1 + 3u;
  x0 += x1; x1 = rotl32(x1, 17); x1 ^= x0;
  x0 += x1; x1 = rotl32(x1, 29); x1 ^= x0;
  x0 += x1; x1 = rotl32(x1, 16); x1 ^= x0;
  x0 += x1; x1 = rotl32(x1, 24); x1 ^= x0;
  x0 += k1; x1 += ks2 + 4u;
  x0 += x1; x1 = rotl32(x1, 13); x1 ^= x0;
  x0 += x1; x1 = rotl32(x1, 15); x1 ^= x0;
  x0 += x1; x1 = rotl32(x1, 26); x1 ^= x0;
  x0 += x1; x1 = rotl32(x1, 6);  x1 ^= x0;
  o0 = x0 + ks2;
  o1 = x1 + k0 + 5u;
}

__device__ int jax_r(int b, int k) {
  uint32_t k1a, k1b, k2a, k2b, h0, h1, l0, l1;
  tf2x32(0u, 42u, 0u, 0u, k1a, k1b);  // split: subkey 0
  tf2x32(0u, 42u, 0u, 1u, k2a, k2b);  // split: subkey 1
  const uint32_t idx = (uint32_t)(b * KK + k);
  tf2x32(k1a, k1b, 0u, idx, h0, h1);
  tf2x32(k2a, k2b, 0u, idx, l0, l1);
  const uint32_t hb = h0 ^ h1, lb = l0 ^ l1;
  return (int)(((hb % 3u) + (lb % 3u)) % 3u);
}

// ---------------------------------------------------------------------------
// Kernel 1: mw[b][d][n] = bias[d] + sum_ci idx_feat[b][ci][n] * weight[d][ci]
// ---------------------------------------------------------------------------
__global__ __launch_bounds__(256) void k_mw(const float* __restrict__ idx_feat,
                                            const float* __restrict__ weight,
                                            const float* __restrict__ bias,
                                            float* __restrict__ mw) {
  const int tid = blockIdx.x * 256 + threadIdx.x;
  if (tid >= NBF * CO * NN) return;
  const int n = tid % NN;
  const int rest = tid / NN;
  const int d = rest % CO;
  const int b = rest / CO;
  float acc = bias[d];
  const float* feat = idx_feat + (size_t)(b * CI) * NN + n;  // stride NN per ci
  const float* wrow = weight + d * CI;
  #pragma unroll 8
  for (int ci = 0; ci < CI; ++ci)
    acc = fmaf(feat[ci * NN], wrow[ci], acc);
  mw[tid] = acc;  // layout [b][d][n]
}

// ---------------------------------------------------------------------------
// Kernel 2: contrastive loss partials. 16 blocks = 2 b * 8 chunks of 25 k.
// ---------------------------------------------------------------------------
__device__ __forceinline__ float waveMax(float v) {
  #pragma unroll
  for (int o = 32; o > 0; o >>= 1) v = fmaxf(v, __shfl_down(v, o));
  return v;
}
__device__ __forceinline__ float waveSum(float v) {
  #pragma unroll
  for (int o = 32; o > 0; o >>= 1) v += __shfl_down(v, o);
  return v;
}

__global__ __launch_bounds__(256) void k_loss(const float* __restrict__ mw,
                                              float* __restrict__ partial) {
  __shared__ __align__(16) float m_lds[KK][68];  // padded rows (54.4 KB)
  __shared__ float red[8];
  __shared__ float pos_sh;
  __shared__ int rvals[32];

  const int b = blockIdx.x >> 3;
  const int chunk = blockIdx.x & 7;
  const int t = threadIdx.x;
  const int wid = t >> 6, lane = t & 63;
  const int kbase = chunk * 25;

  if (t < 25) rvals[t] = jax_r(b, kbase + t);

  float row[CO];
  if (t < KK) {
    const int f = t & 3, ni = t >> 2;
    const float* src = mw + (size_t)((b * 4 + f) * CO) * NN + ni;  // stride NN per c
    float ssq = 0.f;
    #pragma unroll
    for (int c = 0; c < CO; ++c) { const float v = src[c * NN]; row[c] = v; ssq += v * v; }
    const float inv = 1.0f / fmaxf(sqrtf(ssq), 1e-12f);
    #pragma unroll
    for (int c = 0; c < CO; ++c) { row[c] *= inv; m_lds[t][c] = row[c]; }
  }
  __syncthreads();

  float part = 0.f;
  for (int kk = 0; kk < 25; ++kk) {
    const int k = kbase + kk;
    const int g = k >> 2, fo = k & 3;
    const int r = rvals[kk];
    const int pos_off = (r >= fo) ? r + 1 : r;
    const int pos_col = (g << 2) + pos_off;
    const int last_neg = (g == NN - 1) ? (KK - 5) : (KK - 1);  // 195 or 199

    float dot = 0.f;
    if (t < KK) {
      const float4* mk = reinterpret_cast<const float4*>(&m_lds[k][0]);  // broadcast
      #pragma unroll
      for (int c4 = 0; c4 < 16; ++c4) {
        const float4 a = mk[c4];
        dot = fmaf(a.x, row[4 * c4 + 0], dot);
        dot = fmaf(a.y, row[4 * c4 + 1], dot);
        dot = fmaf(a.z, row[4 * c4 + 2], dot);
        dot = fmaf(a.w, row[4 * c4 + 3], dot);
      }
    }
    const float logit = dot * (1.0f / 0.07f);

    float wgt = 0.f;
    if (t < KK) {
      if (t == pos_col) wgt = 1.f;
      else if ((t >> 2) != g) wgt = (t == last_neg) ? 4.f : 1.f;
    }
    const bool valid = wgt > 0.f;

    const float wmax = waveMax(valid ? logit : -FLT_MAX);
    if (lane == 0) red[wid] = wmax;
    if (t == pos_col) pos_sh = logit;
    __syncthreads();
    const float mx = fmaxf(fmaxf(red[0], red[1]), fmaxf(red[2], red[3]));
    const float pos = pos_sh;
    const float ws = waveSum(valid ? wgt * expf(logit - mx) : 0.f);
    if (lane == 0) red[4 + wid] = ws;
    __syncthreads();
    if (t == 0) {
      const float s = red[4] + red[5] + red[6] + red[7];
      part += (mx + logf(s)) - pos;
    }
    __syncthreads();
  }
  if (t == 0) partial[blockIdx.x] = part;
}

// ---------------------------------------------------------------------------
// Kernel 3: inst_pred[b][n][p] = sum_c mw[b][c][n] * x[b][c][p]
// R7 structure (512 threads, in-block n-split, LDS-staged x, prefetch-1-chunk)
// with the spill fixed:
//  - __launch_bounds__(512, 4): 128-VGPR cap (need ~45) -> spill impossible.
//  - #pragma unroll 1 on the chunk loop: no full-unroll live-range explosion.
// ---------------------------------------------------------------------------
#define REP25(M) \
  M(0) M(1) M(2) M(3) M(4) M(5) M(6) M(7) M(8) M(9) \
  M(10) M(11) M(12) M(13) M(14) M(15) M(16) M(17) M(18) M(19) \
  M(20) M(21) M(22) M(23) M(24)

#define ACC_DECL(i) float acc##i = 0.f;
#define ACC_FMA(i)  acc##i = fmaf(kr[i], xv, acc##i);
#define ACC_ST(i)   __builtin_nontemporal_store(acc##i, ob + (size_t)(i) * HW_TOT);

__global__ __launch_bounds__(512, 4) void k_pred(const float* __restrict__ x,
                                                 const float* __restrict__ mw,
                                                 const float* __restrict__ partial,
                                                 float* __restrict__ out) {
  __shared__ float xs[2][CHUNK][256];  // 16 KB

  const int b = blockIdx.y;            // n-slice in [0,8)
  const int p0 = blockIdx.x * 256;     // pixel tile base
  const int u = threadIdx.x;
  const int t = u & 255;                                      // pixel within tile
  const int half = __builtin_amdgcn_readfirstlane(u >> 8);    // n-half (wave-uniform -> SGPR)
  const int srow = u >> 6;             // staging row 0..7
  const int scol = (u & 63) * 4;       // staging float col (16B per thread)

  const float* xb = x + (size_t)b * CO * HW_TOT;
  const float* mwb = mw + b * CO * NN + half * 25;

  // Clamped byte offset for staging (ragged last tile: lanes past the end
  // re-read the last valid 16B; their outputs are masked at the store).
  const int sbyte = min(scol * 4, (HW_TOT - p0) * 4 - 16);

  REP25(ACC_DECL)

  // Prologue: stage chunk 0.
  {
    const char* gp = (const char*)(xb + (size_t)srow * HW_TOT + p0) + sbyte;
    const float4 st = *reinterpret_cast<const float4*>(gp);
    *reinterpret_cast<float4*>(&xs[0][srow][scol]) = st;
  }
  __syncthreads();

  #pragma unroll 1
  for (int g = 0; g < CO / CHUNK; ++g) {
    // Issue chunk g+1's global load BEFORE chunk g's FMAs; its vmcnt wait
    // sits at the ds_write below, ~400 FMA-issue cycles later.
    float4 nst;
    if (g < CO / CHUNK - 1) {
      const char* gp =
          (const char*)(xb + (size_t)((g + 1) * CHUNK + srow) * HW_TOT + p0) + sbyte;
      nst = *reinterpret_cast<const float4*>(gp);
    }

    #pragma unroll
    for (int cc = 0; cc < CHUNK; ++cc) {
      const float xv = xs[g & 1][cc][t];
      const float* kr = mwb + (g * CHUNK + cc) * NN;  // wave-uniform -> s_load
      REP25(ACC_FMA)
    }

    if (g < CO / CHUNK - 1) {
      __syncthreads();  // all waves done reading buf[(g+1)&1]
      *reinterpret_cast<float4*>(&xs[(g + 1) & 1][srow][scol]) = nst;
      __syncthreads();  // writes visible before iter g+1 reads
    }
  }

  const int p = p0 + t;
  if (p < HW_TOT) {
    float* ob = out + (size_t)b * NN * HW_TOT + (size_t)half * 25 * HW_TOT + p;
    REP25(ACC_ST)
  }

  // Loss finalize.
  if (blockIdx.x == 0 && b == 0 && u == 0) {
    float s = 0.f;
    #pragma unroll
    for (int i = 0; i < 16; ++i) s += partial[i];
    out[(size_t)NBF * NN * HW_TOT] = s * (1.0f / KK);  // sum_b mean_k
  }
}

// ---------------------------------------------------------------------------
extern "C" void kernel_launch(void* const* d_in, const int* in_sizes, int n_in,
                              void* d_out, int out_size, void* d_ws, size_t ws_size,
                              hipStream_t stream) {
  const float* x        = (const float*)d_in[0];
  const float* idx_feat = (const float*)d_in[1];
  const float* weight   = (const float*)d_in[2];
  const float* bias     = (const float*)d_in[3];
  float* out = (float*)d_out;

  float* mw = (float*)d_ws;                 // 25600 floats
  float* partial = mw + NBF * CO * NN;      // 16 floats

  hipLaunchKernelGGL(k_mw, dim3((NBF * CO * NN + 255) / 256), dim3(256), 0, stream,
                     idx_feat, weight, bias, mw);
  hipLaunchKernelGGL(k_loss, dim3(16), dim3(256), 0, stream, mw, partial);
  hipLaunchKernelGGL(k_pred, dim3((HW_TOT + 255) / 256, NBF), dim3(512), 0, stream,
                     x, mw, partial, out);
}

// Round 9
// 92.490 us; speedup vs baseline: 1.6646x; 1.6646x over previous
//
#include <hip/hip_runtime.h>
#include <stdint.h>
#include <float.h>
#include <math.h>

// Problem constants (b_n=2, f_num=4, N=50, C_in=256, C=64, h=200, w=336)
#define HW_TOT 67200   // h*w = 64 * 1050 exactly
#define NBF 8          // n = b_n*f_num
#define CO 64          // C
#define CI 256         // C_in
#define NN 50          // N
#define KK 200         // K = N*f_num
#define BN 2           // b_n

// ---------------------------------------------------------------------------
// Threefry-2x32, 20 rounds (JAX partitionable threefry semantics) — verified R1
// ---------------------------------------------------------------------------
__device__ __forceinline__ uint32_t rotl32(uint32_t v, int n) {
  return (v << n) | (v >> (32 - n));
}

__device__ void tf2x32(uint32_t k0, uint32_t k1, uint32_t x0, uint32_t x1,
                       uint32_t& o0, uint32_t& o1) {
  const uint32_t ks2 = k0 ^ k1 ^ 0x1BD11BDAu;
  x0 += k0; x1 += k1;
  x0 += x1; x1 = rotl32(x1, 13); x1 ^= x0;
  x0 += x1; x1 = rotl32(x1, 15); x1 ^= x0;
  x0 += x1; x1 = rotl32(x1, 26); x1 ^= x0;
  x0 += x1; x1 = rotl32(x1, 6);  x1 ^= x0;
  x0 += k1; x1 += ks2 + 1u;
  x0 += x1; x1 = rotl32(x1, 17); x1 ^= x0;
  x0 += x1; x1 = rotl32(x1, 29); x1 ^= x0;
  x0 += x1; x1 = rotl32(x1, 16); x1 ^= x0;
  x0 += x1; x1 = rotl32(x1, 24); x1 ^= x0;
  x0 += ks2; x1 += k0 + 2u;
  x0 += x1; x1 = rotl32(x1, 13); x1 ^= x0;
  x0 += x1; x1 = rotl32(x1, 15); x1 ^= x0;
  x0 += x1; x1 = rotl32(x1, 26); x1 ^= x0;
  x0 += x1; x1 = rotl32(x1, 6);  x1 ^= x0;
  x0 += k0; x1 += k1 + 3u;
  x0 += x1; x1 = rotl32(x1, 17); x1 ^= x0;
  x0 += x1; x1 = rotl32(x1, 29); x1 ^= x0;
  x0 += x1; x1 = rotl32(x1, 16); x1 ^= x0;
  x0 += x1; x1 = rotl32(x1, 24); x1 ^= x0;
  x0 += k1; x1 += ks2 + 4u;
  x0 += x1; x1 = rotl32(x1, 13); x1 ^= x0;
  x0 += x1; x1 = rotl32(x1, 15); x1 ^= x0;
  x0 += x1; x1 = rotl32(x1, 26); x1 ^= x0;
  x0 += x1; x1 = rotl32(x1, 6);  x1 ^= x0;
  o0 = x0 + ks2;
  o1 = x1 + k0 + 5u;
}

__device__ int jax_r(int b, int k) {
  uint32_t k1a, k1b, k2a, k2b, h0, h1, l0, l1;
  tf2x32(0u, 42u, 0u, 0u, k1a, k1b);  // split: subkey 0
  tf2x32(0u, 42u, 0u, 1u, k2a, k2b);  // split: subkey 1
  const uint32_t idx = (uint32_t)(b * KK + k);
  tf2x32(k1a, k1b, 0u, idx, h0, h1);
  tf2x32(k2a, k2b, 0u, idx, l0, l1);
  const uint32_t hb = h0 ^ h1, lb = l0 ^ l1;
  return (int)(((hb % 3u) + (lb % 3u)) % 3u);
}

// ---------------------------------------------------------------------------
// Kernel 1: mw[b][d][n] = bias[d] + sum_ci idx_feat[b][ci][n] * weight[d][ci]
// ---------------------------------------------------------------------------
__global__ __launch_bounds__(256) void k_mw(const float* __restrict__ idx_feat,
                                            const float* __restrict__ weight,
                                            const float* __restrict__ bias,
                                            float* __restrict__ mw) {
  const int tid = blockIdx.x * 256 + threadIdx.x;
  if (tid >= NBF * CO * NN) return;
  const int n = tid % NN;
  const int rest = tid / NN;
  const int d = rest % CO;
  const int b = rest / CO;
  float acc = bias[d];
  const float* feat = idx_feat + (size_t)(b * CI) * NN + n;  // stride NN per ci
  const float* wrow = weight + d * CI;
  #pragma unroll 8
  for (int ci = 0; ci < CI; ++ci)
    acc = fmaf(feat[ci * NN], wrow[ci], acc);
  mw[tid] = acc;  // layout [b][d][n]
}

// ---------------------------------------------------------------------------
// Kernel 2: contrastive loss partials. 16 blocks = 2 b * 8 chunks of 25 k.
// ---------------------------------------------------------------------------
__device__ __forceinline__ float waveMax(float v) {
  #pragma unroll
  for (int o = 32; o > 0; o >>= 1) v = fmaxf(v, __shfl_down(v, o));
  return v;
}
__device__ __forceinline__ float waveSum(float v) {
  #pragma unroll
  for (int o = 32; o > 0; o >>= 1) v += __shfl_down(v, o);
  return v;
}

__global__ __launch_bounds__(256) void k_loss(const float* __restrict__ mw,
                                              float* __restrict__ partial) {
  __shared__ __align__(16) float m_lds[KK][68];  // padded rows (54.4 KB)
  __shared__ float red[8];
  __shared__ float pos_sh;
  __shared__ int rvals[32];

  const int b = blockIdx.x >> 3;
  const int chunk = blockIdx.x & 7;
  const int t = threadIdx.x;
  const int wid = t >> 6, lane = t & 63;
  const int kbase = chunk * 25;

  if (t < 25) rvals[t] = jax_r(b, kbase + t);

  float row[CO];
  if (t < KK) {
    const int f = t & 3, ni = t >> 2;
    const float* src = mw + (size_t)((b * 4 + f) * CO) * NN + ni;  // stride NN per c
    float ssq = 0.f;
    #pragma unroll
    for (int c = 0; c < CO; ++c) { const float v = src[c * NN]; row[c] = v; ssq += v * v; }
    const float inv = 1.0f / fmaxf(sqrtf(ssq), 1e-12f);
    #pragma unroll
    for (int c = 0; c < CO; ++c) { row[c] *= inv; m_lds[t][c] = row[c]; }
  }
  __syncthreads();

  float part = 0.f;
  for (int kk = 0; kk < 25; ++kk) {
    const int k = kbase + kk;
    const int g = k >> 2, fo = k & 3;
    const int r = rvals[kk];
    const int pos_off = (r >= fo) ? r + 1 : r;
    const int pos_col = (g << 2) + pos_off;
    const int last_neg = (g == NN - 1) ? (KK - 5) : (KK - 1);  // 195 or 199

    float dot = 0.f;
    if (t < KK) {
      const float4* mk = reinterpret_cast<const float4*>(&m_lds[k][0]);  // broadcast
      #pragma unroll
      for (int c4 = 0; c4 < 16; ++c4) {
        const float4 a = mk[c4];
        dot = fmaf(a.x, row[4 * c4 + 0], dot);
        dot = fmaf(a.y, row[4 * c4 + 1], dot);
        dot = fmaf(a.z, row[4 * c4 + 2], dot);
        dot = fmaf(a.w, row[4 * c4 + 3], dot);
      }
    }
    const float logit = dot * (1.0f / 0.07f);

    float wgt = 0.f;
    if (t < KK) {
      if (t == pos_col) wgt = 1.f;
      else if ((t >> 2) != g) wgt = (t == last_neg) ? 4.f : 1.f;
    }
    const bool valid = wgt > 0.f;

    const float wmax = waveMax(valid ? logit : -FLT_MAX);
    if (lane == 0) red[wid] = wmax;
    if (t == pos_col) pos_sh = logit;
    __syncthreads();
    const float mx = fmaxf(fmaxf(red[0], red[1]), fmaxf(red[2], red[3]));
    const float pos = pos_sh;
    const float ws = waveSum(valid ? wgt * expf(logit - mx) : 0.f);
    if (lane == 0) red[4 + wid] = ws;
    __syncthreads();
    if (t == 0) {
      const float s = red[4] + red[5] + red[6] + red[7];
      part += (mx + logf(s)) - pos;
    }
    __syncthreads();
  }
  if (t == 0) partial[blockIdx.x] = part;
}

// ---------------------------------------------------------------------------
// Kernel 3 (MFMA): inst_pred[b][n][p] = sum_c mw[b][c][n] * x[b][c][p]
// GEMM  D[n][p] = A[n][c] * B[c][p],  A = mw^T (bf16), B = x (bf16), fp32 acc.
// One 64n x 64p tile per block (no inner loop): block-level parallelism
// provides the memory-level parallelism that source pipelining couldn't.
//  - stage x [64c][64p] fp32 -> LDS transposed [p][c] bf16, XOR-swizzled
//  - B-frag = one ds_read_b128 (2-way bank alias only)
//  - wave w owns n-subtile [16w,16w+16): 2 k-steps x 4 p-tiles = 8 MFMA
// ---------------------------------------------------------------------------
typedef __attribute__((ext_vector_type(8))) short bf16x8;
typedef __attribute__((ext_vector_type(4))) float f32x4;

__device__ __forceinline__ uint32_t bf16rne(float f) {
  uint32_t u = __builtin_bit_cast(uint32_t, f);
  return (u + 0x7FFFu + ((u >> 16) & 1u)) >> 16;
}

__global__ __launch_bounds__(256, 4) void k_pred(const float* __restrict__ x,
                                                 const float* __restrict__ mw,
                                                 const float* __restrict__ partial,
                                                 float* __restrict__ out) {
  __shared__ __align__(16) char lds[64 * 128];  // [p=64][c=64] bf16, swizzled

  const int b = blockIdx.y;
  const int p0 = blockIdx.x * 64;
  const int u = threadIdx.x;
  const int l = u & 63;        // lane
  const int w = u >> 6;        // wave 0..3 -> n-subtile base 16*w
  const int ln = l & 15, lg = l >> 4;

  const float* xb  = x  + (size_t)b * CO * HW_TOT;
  const float* mwb = mw + (size_t)b * CO * NN;

  // ---- staging loads: 4 independent coalesced float4 (1 KB/wave each) ----
  const int sc0 = 4 * (u >> 4);   // c rows sc0..sc0+3
  const int sp0 = 4 * (u & 15);   // local p cols sp0..sp0+3
  const float4 v0 = *reinterpret_cast<const float4*>(xb + (size_t)(sc0 + 0) * HW_TOT + p0 + sp0);
  const float4 v1 = *reinterpret_cast<const float4*>(xb + (size_t)(sc0 + 1) * HW_TOT + p0 + sp0);
  const float4 v2 = *reinterpret_cast<const float4*>(xb + (size_t)(sc0 + 2) * HW_TOT + p0 + sp0);
  const float4 v3 = *reinterpret_cast<const float4*>(xb + (size_t)(sc0 + 3) * HW_TOT + p0 + sp0);

  // ---- A-fragments from mw (L1/L2-hot, 12.8 KB per b), n clamped ----
  bf16x8 afr[2];
  #pragma unroll
  for (int ks = 0; ks < 2; ++ks) {
    #pragma unroll
    for (int j = 0; j < 8; ++j) {
      const int c = ks * 32 + lg * 8 + j;
      const int n = min(16 * w + ln, NN - 1);   // rows >=50 garbage, masked at store
      afr[ks][j] = (short)bf16rne(mwb[c * NN + n]);
    }
  }

  // ---- transpose 4x4 micro-tile in registers -> bf16 -> swizzled LDS ----
  {
    const float c0s[4] = {v0.x, v1.x, v2.x, v3.x};
    const float c1s[4] = {v0.y, v1.y, v2.y, v3.y};
    const float c2s[4] = {v0.z, v1.z, v2.z, v3.z};
    const float c3s[4] = {v0.w, v1.w, v2.w, v3.w};
    const float* cols[4] = {c0s, c1s, c2s, c3s};
    #pragma unroll
    for (int s = 0; s < 4; ++s) {
      const float* cv = cols[s];                 // x[sc0+r][p0+sp0+s], r=0..3
      const uint32_t lo = bf16rne(cv[0]) | (bf16rne(cv[1]) << 16);
      const uint32_t hi = bf16rne(cv[2]) | (bf16rne(cv[3]) << 16);
      const int row = sp0 + s;
      const int wb = (row * 128 + sc0 * 2) ^ ((row & 7) << 4);
      *reinterpret_cast<uint2*>(lds + wb) = make_uint2(lo, hi);
    }
  }
  __syncthreads();

  // ---- MFMA: 2 k-steps x 4 p-subtiles ----
  f32x4 acc[4];
  #pragma unroll
  for (int q = 0; q < 4; ++q) acc[q] = (f32x4){0.f, 0.f, 0.f, 0.f};

  #pragma unroll
  for (int ks = 0; ks < 2; ++ks) {
    #pragma unroll
    for (int q = 0; q < 4; ++q) {
      const int row = q * 16 + ln;               // local p
      const int rb = (row * 128 + ks * 64 + lg * 16) ^ ((ln & 7) << 4);
      const uint4 raw = *reinterpret_cast<const uint4*>(lds + rb);
      const bf16x8 bfr = __builtin_bit_cast(bf16x8, raw);
      acc[q] = __builtin_amdgcn_mfma_f32_16x16x32_bf16(afr[ks], bfr, acc[q], 0, 0, 0);
    }
  }

  // ---- epilogue: D[row=(lg*4+i)][col=ln] per p-subtile, mask n>=50 ----
  float* ob = out + (size_t)b * NN * HW_TOT + p0;
  #pragma unroll
  for (int q = 0; q < 4; ++q) {
    #pragma unroll
    for (int i = 0; i < 4; ++i) {
      const int n = 16 * w + 4 * lg + i;
      if (n < NN)
        __builtin_nontemporal_store(acc[q][i], ob + (size_t)n * HW_TOT + q * 16 + ln);
    }
  }

  // Loss finalize.
  if (blockIdx.x == 0 && b == 0 && u == 0) {
    float s = 0.f;
    #pragma unroll
    for (int i = 0; i < 16; ++i) s += partial[i];
    out[(size_t)NBF * NN * HW_TOT] = s * (1.0f / KK);  // sum_b mean_k
  }
}

// ---------------------------------------------------------------------------
extern "C" void kernel_launch(void* const* d_in, const int* in_sizes, int n_in,
                              void* d_out, int out_size, void* d_ws, size_t ws_size,
                              hipStream_t stream) {
  const float* x        = (const float*)d_in[0];
  const float* idx_feat = (const float*)d_in[1];
  const float* weight   = (const float*)d_in[2];
  const float* bias     = (const float*)d_in[3];
  float* out = (float*)d_out;

  float* mw = (float*)d_ws;                 // 25600 floats
  float* partial = mw + NBF * CO * NN;      // 16 floats

  hipLaunchKernelGGL(k_mw, dim3((NBF * CO * NN + 255) / 256), dim3(256), 0, stream,
                     idx_feat, weight, bias, mw);
  hipLaunchKernelGGL(k_loss, dim3(16), dim3(256), 0, stream, mw, partial);
  hipLaunchKernelGGL(k_pred, dim3(HW_TOT / 64, NBF), dim3(256), 0, stream,
                     x, mw, partial, out);
}

// Round 10
// 88.004 us; speedup vs baseline: 1.7495x; 1.0510x over previous
//
#include <hip/hip_runtime.h>
#include <stdint.h>
#include <float.h>
#include <math.h>

// Problem constants (b_n=2, f_num=4, N=50, C_in=256, C=64, h=200, w=336)
#define HW_TOT 67200   // h*w = 64 * 1050 = 320 * 210
#define NBF 8          // n = b_n*f_num
#define CO 64          // C
#define CI 256         // C_in
#define NN 50          // N
#define KK 200         // K = N*f_num
#define BN 2           // b_n
#define TILES 5        // 64-px tiles swept per block (p-contiguity)

// ---------------------------------------------------------------------------
// Threefry-2x32, 20 rounds (JAX partitionable threefry semantics) — verified R1
// ---------------------------------------------------------------------------
__device__ __forceinline__ uint32_t rotl32(uint32_t v, int n) {
  return (v << n) | (v >> (32 - n));
}

__device__ void tf2x32(uint32_t k0, uint32_t k1, uint32_t x0, uint32_t x1,
                       uint32_t& o0, uint32_t& o1) {
  const uint32_t ks2 = k0 ^ k1 ^ 0x1BD11BDAu;
  x0 += k0; x1 += k1;
  x0 += x1; x1 = rotl32(x1, 13); x1 ^= x0;
  x0 += x1; x1 = rotl32(x1, 15); x1 ^= x0;
  x0 += x1; x1 = rotl32(x1, 26); x1 ^= x0;
  x0 += x1; x1 = rotl32(x1, 6);  x1 ^= x0;
  x0 += k1; x1 += ks2 + 1u;
  x0 += x1; x1 = rotl32(x1, 17); x1 ^= x0;
  x0 += x1; x1 = rotl32(x1, 29); x1 ^= x0;
  x0 += x1; x1 = rotl32(x1, 16); x1 ^= x0;
  x0 += x1; x1 = rotl32(x1, 24); x1 ^= x0;
  x0 += ks2; x1 += k0 + 2u;
  x0 += x1; x1 = rotl32(x1, 13); x1 ^= x0;
  x0 += x1; x1 = rotl32(x1, 15); x1 ^= x0;
  x0 += x1; x1 = rotl32(x1, 26); x1 ^= x0;
  x0 += x1; x1 = rotl32(x1, 6);  x1 ^= x0;
  x0 += k0; x1 += k1 + 3u;
  x0 += x1; x1 = rotl32(x1, 17); x1 ^= x0;
  x0 += x1; x1 = rotl32(x1, 29); x1 ^= x0;
  x0 += x1; x1 = rotl32(x1, 16); x1 ^= x0;
  x0 += x1; x1 = rotl32(x1, 24); x1 ^= x0;
  x0 += k1; x1 += ks2 + 4u;
  x0 += x1; x1 = rotl32(x1, 13); x1 ^= x0;
  x0 += x1; x1 = rotl32(x1, 15); x1 ^= x0;
  x0 += x1; x1 = rotl32(x1, 26); x1 ^= x0;
  x0 += x1; x1 = rotl32(x1, 6);  x1 ^= x0;
  o0 = x0 + ks2;
  o1 = x1 + k0 + 5u;
}

__device__ int jax_r(int b, int k) {
  uint32_t k1a, k1b, k2a, k2b, h0, h1, l0, l1;
  tf2x32(0u, 42u, 0u, 0u, k1a, k1b);  // split: subkey 0
  tf2x32(0u, 42u, 0u, 1u, k2a, k2b);  // split: subkey 1
  const uint32_t idx = (uint32_t)(b * KK + k);
  tf2x32(k1a, k1b, 0u, idx, h0, h1);
  tf2x32(k2a, k2b, 0u, idx, l0, l1);
  const uint32_t hb = h0 ^ h1, lb = l0 ^ l1;
  return (int)(((hb % 3u) + (lb % 3u)) % 3u);
}

// ---------------------------------------------------------------------------
// Kernel 1: mw[b][d][n] = bias[d] + sum_ci idx_feat[b][ci][n] * weight[d][ci]
// ---------------------------------------------------------------------------
__global__ __launch_bounds__(256) void k_mw(const float* __restrict__ idx_feat,
                                            const float* __restrict__ weight,
                                            const float* __restrict__ bias,
                                            float* __restrict__ mw) {
  const int tid = blockIdx.x * 256 + threadIdx.x;
  if (tid >= NBF * CO * NN) return;
  const int n = tid % NN;
  const int rest = tid / NN;
  const int d = rest % CO;
  const int b = rest / CO;
  float acc = bias[d];
  const float* feat = idx_feat + (size_t)(b * CI) * NN + n;  // stride NN per ci
  const float* wrow = weight + d * CI;
  #pragma unroll 8
  for (int ci = 0; ci < CI; ++ci)
    acc = fmaf(feat[ci * NN], wrow[ci], acc);
  mw[tid] = acc;  // layout [b][d][n]
}

// ---------------------------------------------------------------------------
// Kernel 2: contrastive loss partials. 16 blocks = 2 b * 8 chunks of 25 k.
// ---------------------------------------------------------------------------
__device__ __forceinline__ float waveMax(float v) {
  #pragma unroll
  for (int o = 32; o > 0; o >>= 1) v = fmaxf(v, __shfl_down(v, o));
  return v;
}
__device__ __forceinline__ float waveSum(float v) {
  #pragma unroll
  for (int o = 32; o > 0; o >>= 1) v += __shfl_down(v, o);
  return v;
}

__global__ __launch_bounds__(256) void k_loss(const float* __restrict__ mw,
                                              float* __restrict__ partial) {
  __shared__ __align__(16) float m_lds[KK][68];  // padded rows (54.4 KB)
  __shared__ float red[8];
  __shared__ float pos_sh;
  __shared__ int rvals[32];

  const int b = blockIdx.x >> 3;
  const int chunk = blockIdx.x & 7;
  const int t = threadIdx.x;
  const int wid = t >> 6, lane = t & 63;
  const int kbase = chunk * 25;

  if (t < 25) rvals[t] = jax_r(b, kbase + t);

  float row[CO];
  if (t < KK) {
    const int f = t & 3, ni = t >> 2;
    const float* src = mw + (size_t)((b * 4 + f) * CO) * NN + ni;  // stride NN per c
    float ssq = 0.f;
    #pragma unroll
    for (int c = 0; c < CO; ++c) { const float v = src[c * NN]; row[c] = v; ssq += v * v; }
    const float inv = 1.0f / fmaxf(sqrtf(ssq), 1e-12f);
    #pragma unroll
    for (int c = 0; c < CO; ++c) { row[c] *= inv; m_lds[t][c] = row[c]; }
  }
  __syncthreads();

  float part = 0.f;
  for (int kk = 0; kk < 25; ++kk) {
    const int k = kbase + kk;
    const int g = k >> 2, fo = k & 3;
    const int r = rvals[kk];
    const int pos_off = (r >= fo) ? r + 1 : r;
    const int pos_col = (g << 2) + pos_off;
    const int last_neg = (g == NN - 1) ? (KK - 5) : (KK - 1);  // 195 or 199

    float dot = 0.f;
    if (t < KK) {
      const float4* mk = reinterpret_cast<const float4*>(&m_lds[k][0]);  // broadcast
      #pragma unroll
      for (int c4 = 0; c4 < 16; ++c4) {
        const float4 a = mk[c4];
        dot = fmaf(a.x, row[4 * c4 + 0], dot);
        dot = fmaf(a.y, row[4 * c4 + 1], dot);
        dot = fmaf(a.z, row[4 * c4 + 2], dot);
        dot = fmaf(a.w, row[4 * c4 + 3], dot);
      }
    }
    const float logit = dot * (1.0f / 0.07f);

    float wgt = 0.f;
    if (t < KK) {
      if (t == pos_col) wgt = 1.f;
      else if ((t >> 2) != g) wgt = (t == last_neg) ? 4.f : 1.f;
    }
    const bool valid = wgt > 0.f;

    const float wmax = waveMax(valid ? logit : -FLT_MAX);
    if (lane == 0) red[wid] = wmax;
    if (t == pos_col) pos_sh = logit;
    __syncthreads();
    const float mx = fmaxf(fmaxf(red[0], red[1]), fmaxf(red[2], red[3]));
    const float pos = pos_sh;
    const float ws = waveSum(valid ? wgt * expf(logit - mx) : 0.f);
    if (lane == 0) red[4 + wid] = ws;
    __syncthreads();
    if (t == 0) {
      const float s = red[4] + red[5] + red[6] + red[7];
      part += (mx + logf(s)) - pos;
    }
    __syncthreads();
  }
  if (t == 0) partial[blockIdx.x] = part;
}

// ---------------------------------------------------------------------------
// Kernel 3 (MFMA): inst_pred[b][n][p] = sum_c mw[b][c][n] * x[b][c][p]
// R9 MFMA structure + p-SWEEP: each block walks TILES consecutive 64-px
// tiles, so per-c-row HBM reads and per-n-row writes become sequential
// (1.28 KB streams instead of isolated 256 B touches -> DRAM page locality).
// Plain (non-NT) stores let L2 aggregate full 128B lines (R9 WRITE was 1.3x).
// ---------------------------------------------------------------------------
typedef __attribute__((ext_vector_type(8))) short bf16x8;
typedef __attribute__((ext_vector_type(4))) float f32x4;

__device__ __forceinline__ uint32_t bf16rne(float f) {
  uint32_t u = __builtin_bit_cast(uint32_t, f);
  return (u + 0x7FFFu + ((u >> 16) & 1u)) >> 16;
}

__global__ __launch_bounds__(256, 4) void k_pred(const float* __restrict__ x,
                                                 const float* __restrict__ mw,
                                                 const float* __restrict__ partial,
                                                 float* __restrict__ out) {
  __shared__ __align__(16) char lds[64 * 128];  // [p=64][c=64] bf16, swizzled

  const int b = blockIdx.y;
  const int u = threadIdx.x;
  const int l = u & 63;        // lane
  const int w = u >> 6;        // wave 0..3 -> n-subtile base 16*w
  const int ln = l & 15, lg = l >> 4;

  const float* xb  = x  + (size_t)b * CO * HW_TOT;
  const float* mwb = mw + (size_t)b * CO * NN;

  const int sc0 = 4 * (u >> 4);   // c rows sc0..sc0+3
  const int sp0 = 4 * (u & 15);   // local p cols sp0..sp0+3
  const int pbase = blockIdx.x * (64 * TILES);

  // ---- A-fragments from mw (L1/L2-hot), once per block; n clamped ----
  bf16x8 afr[2];
  #pragma unroll
  for (int ks = 0; ks < 2; ++ks) {
    #pragma unroll
    for (int j = 0; j < 8; ++j) {
      const int c = ks * 32 + lg * 8 + j;
      const int n = min(16 * w + ln, NN - 1);   // rows >=50 garbage, masked at store
      afr[ks][j] = (short)bf16rne(mwb[c * NN + n]);
    }
  }

  // ---- prologue: load tile 0 (4 independent coalesced float4) ----
  float4 v0, v1, v2, v3;
  {
    const float* src = xb + (size_t)sc0 * HW_TOT + pbase + sp0;
    v0 = *reinterpret_cast<const float4*>(src);
    v1 = *reinterpret_cast<const float4*>(src + HW_TOT);
    v2 = *reinterpret_cast<const float4*>(src + 2 * (size_t)HW_TOT);
    v3 = *reinterpret_cast<const float4*>(src + 3 * (size_t)HW_TOT);
  }

  #pragma unroll 1
  for (int t = 0; t < TILES; ++t) {
    if (t > 0) __syncthreads();  // all waves done reading prev tile's LDS

    // ---- transpose 4x4 micro-tile -> bf16 -> swizzled LDS ----
    {
      const float c0s[4] = {v0.x, v1.x, v2.x, v3.x};
      const float c1s[4] = {v0.y, v1.y, v2.y, v3.y};
      const float c2s[4] = {v0.z, v1.z, v2.z, v3.z};
      const float c3s[4] = {v0.w, v1.w, v2.w, v3.w};
      const float* cols[4] = {c0s, c1s, c2s, c3s};
      #pragma unroll
      for (int s = 0; s < 4; ++s) {
        const float* cv = cols[s];               // x[sc0+r][pbase+t*64+sp0+s]
        const uint32_t lo = bf16rne(cv[0]) | (bf16rne(cv[1]) << 16);
        const uint32_t hi = bf16rne(cv[2]) | (bf16rne(cv[3]) << 16);
        const int row = sp0 + s;
        const int wb = (row * 128 + sc0 * 2) ^ ((row & 7) << 4);
        *reinterpret_cast<uint2*>(lds + wb) = make_uint2(lo, hi);
      }
    }
    __syncthreads();

    // ---- issue next tile's loads (overlap MFMA + stores below) ----
    if (t + 1 < TILES) {
      const float* src = xb + (size_t)sc0 * HW_TOT + pbase + (t + 1) * 64 + sp0;
      v0 = *reinterpret_cast<const float4*>(src);
      v1 = *reinterpret_cast<const float4*>(src + HW_TOT);
      v2 = *reinterpret_cast<const float4*>(src + 2 * (size_t)HW_TOT);
      v3 = *reinterpret_cast<const float4*>(src + 3 * (size_t)HW_TOT);
    }

    // ---- MFMA: 2 k-steps x 4 p-subtiles ----
    f32x4 acc[4];
    #pragma unroll
    for (int q = 0; q < 4; ++q) acc[q] = (f32x4){0.f, 0.f, 0.f, 0.f};

    #pragma unroll
    for (int ks = 0; ks < 2; ++ks) {
      #pragma unroll
      for (int q = 0; q < 4; ++q) {
        const int row = q * 16 + ln;             // local p
        const int rb = (row * 128 + ks * 64 + lg * 16) ^ ((ln & 7) << 4);
        const uint4 raw = *reinterpret_cast<const uint4*>(lds + rb);
        const bf16x8 bfr = __builtin_bit_cast(bf16x8, raw);
        acc[q] = __builtin_amdgcn_mfma_f32_16x16x32_bf16(afr[ks], bfr, acc[q], 0, 0, 0);
      }
    }

    // ---- epilogue: plain stores, i outer / q inner (line-friendly) ----
    float* ob = out + (size_t)b * NN * HW_TOT + pbase + t * 64;
    #pragma unroll
    for (int i = 0; i < 4; ++i) {
      const int n = 16 * w + 4 * lg + i;
      if (n < NN) {
        float* orow = ob + (size_t)n * HW_TOT + ln;
        #pragma unroll
        for (int q = 0; q < 4; ++q)
          orow[q * 16] = acc[q][i];
      }
    }
  }

  // Loss finalize.
  if (blockIdx.x == 0 && b == 0 && u == 0) {
    float s = 0.f;
    #pragma unroll
    for (int i = 0; i < 16; ++i) s += partial[i];
    out[(size_t)NBF * NN * HW_TOT] = s * (1.0f / KK);  // sum_b mean_k
  }
}

// ---------------------------------------------------------------------------
extern "C" void kernel_launch(void* const* d_in, const int* in_sizes, int n_in,
                              void* d_out, int out_size, void* d_ws, size_t ws_size,
                              hipStream_t stream) {
  const float* x        = (const float*)d_in[0];
  const float* idx_feat = (const float*)d_in[1];
  const float* weight   = (const float*)d_in[2];
  const float* bias     = (const float*)d_in[3];
  float* out = (float*)d_out;

  float* mw = (float*)d_ws;                 // 25600 floats
  float* partial = mw + NBF * CO * NN;      // 16 floats

  hipLaunchKernelGGL(k_mw, dim3((NBF * CO * NN + 255) / 256), dim3(256), 0, stream,
                     idx_feat, weight, bias, mw);
  hipLaunchKernelGGL(k_loss, dim3(16), dim3(256), 0, stream, mw, partial);
  hipLaunchKernelGGL(k_pred, dim3(HW_TOT / (64 * TILES), NBF), dim3(256), 0, stream,
                     x, mw, partial, out);
}